// Round 1
// baseline (1258.509 us; speedup 1.0000x reference)
//
#include <hip/hip_runtime.h>
#include <math.h>

#define T_TOK 8192
#define DDIM  1024
#define HDIM  4096
#define NEXP  8
#define BM    128
#define MAXROWS (T_TOK*2 + NEXP*BM)   /* 17408 */
#define MAXTILES (MAXROWS/BM)         /* 136 */
#define LDA   40                      /* LDS row stride in shorts: 80B = 5*16B -> conflict-free b128 */

typedef __attribute__((ext_vector_type(8))) short short8;
typedef __attribute__((ext_vector_type(4))) short short4v;
typedef __attribute__((ext_vector_type(4))) float f32x4;

__device__ __forceinline__ short f2bf(float f) {
  unsigned u = __float_as_uint(f);
  u += 0x7fffu + ((u >> 16) & 1u);   // RNE
  return (short)(u >> 16);
}

// ---------------- gating ----------------
__global__ __launch_bounds__(256) void k_gate(const float* __restrict__ x,
    const float* __restrict__ gw, const float* __restrict__ gb,
    int2* __restrict__ toke, float2* __restrict__ tokw, int* __restrict__ cnt) {
  __shared__ float sg[NEXP * DDIM];           // transposed [e][d], 32 KB
  for (int i = threadIdx.x; i < NEXP * DDIM; i += 256) {
    int e = i >> 10, d = i & (DDIM - 1);
    sg[i] = gw[d * NEXP + e];
  }
  __syncthreads();
  int wave = threadIdx.x >> 6, lane = threadIdx.x & 63;
  int tok0 = blockIdx.x * (T_TOK / 64);       // 128 tokens per block
  for (int tt = wave; tt < T_TOK / 64; tt += 4) {
    int tok = tok0 + tt;
    float p[NEXP];
#pragma unroll
    for (int e = 0; e < NEXP; e++) p[e] = 0.f;
#pragma unroll
    for (int c = 0; c < 4; c++) {
      int d = c * 256 + lane * 4;
      float4 xv = *(const float4*)&x[(size_t)tok * DDIM + d];
#pragma unroll
      for (int e = 0; e < NEXP; e++) {
        float4 g = *(const float4*)&sg[e * DDIM + d];
        p[e] += xv.x * g.x + xv.y * g.y + xv.z * g.z + xv.w * g.w;
      }
    }
#pragma unroll
    for (int off = 32; off; off >>= 1)
#pragma unroll
      for (int e = 0; e < NEXP; e++) p[e] += __shfl_xor(p[e], off);
    if (lane == 0) {
      float l[NEXP];
#pragma unroll
      for (int e = 0; e < NEXP; e++) l[e] = p[e] + gb[e];
      int i0 = 0;
#pragma unroll
      for (int e = 1; e < NEXP; e++) if (l[e] > l[i0]) i0 = e;   // first-max (jax tie-break)
      int i1 = (i0 == 0) ? 1 : 0;
#pragma unroll
      for (int e = 0; e < NEXP; e++) if (e != i0 && l[e] > l[i1]) i1 = e;
      // renormalized top-2 softmax == softmax over the two top logits
      float ex = expf(l[i1] - l[i0]);
      float w0 = 1.f / (1.f + ex);
      toke[tok] = make_int2(i0, i1);
      tokw[tok] = make_float2(w0, 1.f - w0);
      atomicAdd(&cnt[i0], 1);
      atomicAdd(&cnt[i1], 1);
    }
  }
}

// ---------------- routing plan ----------------
__global__ void k_plan(const int* __restrict__ cnt, int* __restrict__ pbase,
                       int* __restrict__ texp) {
  if (threadIdx.x == 0 && blockIdx.x == 0) {
    int base = 0;
    for (int e = 0; e < NEXP; e++) {
      pbase[e] = base;
      int pc = (cnt[e] + BM - 1) & ~(BM - 1);   // pad each expert to tile multiple
      for (int t = base / BM; t < (base + pc) / BM; ++t) texp[t] = e;
      base += pc;
    }
    for (int t = base / BM; t < MAXTILES; ++t) texp[t] = -1;
  }
}

__global__ __launch_bounds__(256) void k_scatter(const int2* __restrict__ toke,
    const float2* __restrict__ tokw, const int* __restrict__ pbase,
    int* __restrict__ fill, int* __restrict__ rtok, float* __restrict__ rwgt) {
  int tok = blockIdx.x * 256 + threadIdx.x;
  if (tok >= T_TOK) return;
  int2 te = toke[tok];
  float2 tw = tokw[tok];
  int s0 = atomicAdd(&fill[te.x], 1);
  int r0 = pbase[te.x] + s0;
  rtok[r0] = tok; rwgt[r0] = tw.x;
  int s1 = atomicAdd(&fill[te.y], 1);
  int r1 = pbase[te.y] + s1;
  rtok[r1] = tok; rwgt[r1] = tw.y;
}

// ---------------- stage 1: h = gelu(x @ w1[e] + b1[e]) ----------------
__global__ __launch_bounds__(256) void k_ffn1(const float* __restrict__ x,
    const float* __restrict__ w1, const float* __restrict__ b1,
    const int* __restrict__ rtok, const int* __restrict__ texp,
    int tile_base, short* __restrict__ hbuf) {
  int tm = tile_base + blockIdx.x;
  int e = texp[tm];
  if (e < 0) return;
  int n0 = blockIdx.y * 128;
  const float* W = w1 + (size_t)e * DDIM * HDIM;
  __shared__ short Al[128 * LDA];
  __shared__ short Bl[128 * LDA];
  int t = threadIdx.x;
  int ar  = t >> 3;          // A strip base row (+ i*32)
  int aks = (t & 7) * 4;     // A strip k offset
  int bn  = t & 127;         // B column
  int bkq = t >> 7;          // B k-quad base (+ i*2)
  int atok[4];
#pragma unroll
  for (int i = 0; i < 4; i++) atok[i] = rtok[tm * BM + ar + i * 32];

  f32x4 acc[4][4];
#pragma unroll
  for (int i = 0; i < 4; i++)
#pragma unroll
    for (int j = 0; j < 4; j++) acc[i][j] = (f32x4){0.f, 0.f, 0.f, 0.f};

  int wid = t >> 6, lane = t & 63;
  int wm = (wid >> 1) * 64, wn = (wid & 1) * 64;
  int lr = lane & 15, kg = lane >> 4;

  for (int kt = 0; kt < DDIM / 32; ++kt) {
    int k0 = kt * 32;
    __syncthreads();
#pragma unroll
    for (int i = 0; i < 4; i++) {
      float4 xv = make_float4(0.f, 0.f, 0.f, 0.f);
      if (atok[i] >= 0) xv = *(const float4*)&x[(size_t)atok[i] * DDIM + k0 + aks];
      short4v s;
      s[0] = f2bf(xv.x); s[1] = f2bf(xv.y); s[2] = f2bf(xv.z); s[3] = f2bf(xv.w);
      *(short4v*)&Al[(ar + i * 32) * LDA + aks] = s;
    }
#pragma unroll
    for (int i = 0; i < 4; i++) {
      int kq = bkq + i * 2;
      const float* wp = W + (size_t)(k0 + kq * 4) * HDIM + n0 + bn;
      short4v s;
      s[0] = f2bf(wp[0]); s[1] = f2bf(wp[HDIM]);
      s[2] = f2bf(wp[2 * HDIM]); s[3] = f2bf(wp[3 * HDIM]);
      *(short4v*)&Bl[bn * LDA + kq * 4] = s;   // B stored [n][k]
    }
    __syncthreads();
    short8 af[4], bg[4];
#pragma unroll
    for (int i = 0; i < 4; i++) af[i] = *(short8*)&Al[(wm + i * 16 + lr) * LDA + kg * 8];
#pragma unroll
    for (int j = 0; j < 4; j++) bg[j] = *(short8*)&Bl[(wn + j * 16 + lr) * LDA + kg * 8];
#pragma unroll
    for (int i = 0; i < 4; i++)
#pragma unroll
      for (int j = 0; j < 4; j++)
        acc[i][j] = __builtin_amdgcn_mfma_f32_16x16x32_bf16(af[i], bg[j], acc[i][j], 0, 0, 0);
  }

#pragma unroll
  for (int j = 0; j < 4; j++) {
    int gcol = n0 + wn + j * 16 + lr;
    float bias = b1[e * HDIM + gcol];
#pragma unroll
    for (int i = 0; i < 4; i++) {
      int rl = wm + i * 16 + kg * 4;
#pragma unroll
      for (int r = 0; r < 4; r++) {
        float v = acc[i][j][r] + bias;
        v = 0.5f * v * (1.f + erff(v * 0.70710678118f));   // exact gelu
        hbuf[(size_t)(blockIdx.x * BM + rl + r) * HDIM + gcol] = f2bf(v);
      }
    }
  }
}

// ---------------- stage 2: out[tok] += wgt * (h @ w2[e] + b2[e]) ----------------
__global__ __launch_bounds__(256) void k_ffn2(const short* __restrict__ hbuf,
    const float* __restrict__ w2, const float* __restrict__ b2,
    const int* __restrict__ rtok, const float* __restrict__ rwgt,
    const int* __restrict__ texp, int tile_base, float* __restrict__ out) {
  int tm = tile_base + blockIdx.x;
  int e = texp[tm];
  if (e < 0) return;
  int n0 = blockIdx.y * 128;
  const float* W = w2 + (size_t)e * HDIM * DDIM;
  __shared__ short Al[128 * LDA];
  __shared__ short Bl[128 * LDA];
  int t = threadIdx.x;
  int ar  = t >> 2;          // + i*64
  int aks = (t & 3) * 8;
  int bn  = t & 127;
  int bkq = t >> 7;

  f32x4 acc[4][4];
#pragma unroll
  for (int i = 0; i < 4; i++)
#pragma unroll
    for (int j = 0; j < 4; j++) acc[i][j] = (f32x4){0.f, 0.f, 0.f, 0.f};

  int wid = t >> 6, lane = t & 63;
  int wm = (wid >> 1) * 64, wn = (wid & 1) * 64;
  int lr = lane & 15, kg = lane >> 4;

  for (int kt = 0; kt < HDIM / 32; ++kt) {
    int k0 = kt * 32;
    __syncthreads();
#pragma unroll
    for (int i = 0; i < 2; i++) {
      short8 v = *(const short8*)&hbuf[(size_t)(blockIdx.x * BM + ar + i * 64) * HDIM + k0 + aks];
      *(short8*)&Al[(ar + i * 64) * LDA + aks] = v;
    }
#pragma unroll
    for (int i = 0; i < 4; i++) {
      int kq = bkq + i * 2;
      const float* wp = W + (size_t)(k0 + kq * 4) * DDIM + n0 + bn;
      short4v s;
      s[0] = f2bf(wp[0]); s[1] = f2bf(wp[DDIM]);
      s[2] = f2bf(wp[2 * DDIM]); s[3] = f2bf(wp[3 * DDIM]);
      *(short4v*)&Bl[bn * LDA + kq * 4] = s;
    }
    __syncthreads();
    short8 af[4], bg[4];
#pragma unroll
    for (int i = 0; i < 4; i++) af[i] = *(short8*)&Al[(wm + i * 16 + lr) * LDA + kg * 8];
#pragma unroll
    for (int j = 0; j < 4; j++) bg[j] = *(short8*)&Bl[(wn + j * 16 + lr) * LDA + kg * 8];
#pragma unroll
    for (int i = 0; i < 4; i++)
#pragma unroll
      for (int j = 0; j < 4; j++)
        acc[i][j] = __builtin_amdgcn_mfma_f32_16x16x32_bf16(af[i], bg[j], acc[i][j], 0, 0, 0);
  }

#pragma unroll
  for (int j = 0; j < 4; j++) {
    int gcol = n0 + wn + j * 16 + lr;
    float bias = b2[e * DDIM + gcol];
#pragma unroll
    for (int i = 0; i < 4; i++) {
      int rl = wm + i * 16 + kg * 4;
#pragma unroll
      for (int r = 0; r < 4; r++) {
        int grow = tm * BM + rl + r;
        int tok = rtok[grow];
        if (tok >= 0) {
          float v = (acc[i][j][r] + bias) * rwgt[grow];
          atomicAdd(&out[(size_t)tok * DDIM + gcol], v);
        }
      }
    }
  }
}

extern "C" void kernel_launch(void* const* d_in, const int* in_sizes, int n_in,
                              void* d_out, int out_size, void* d_ws, size_t ws_size,
                              hipStream_t stream) {
  const float* x  = (const float*)d_in[0];
  const float* gw = (const float*)d_in[1];
  const float* gb = (const float*)d_in[2];
  const float* w1 = (const float*)d_in[3];
  const float* b1 = (const float*)d_in[4];
  const float* w2 = (const float*)d_in[5];
  const float* b2 = (const float*)d_in[6];
  float* out = (float*)d_out;
  char* ws = (char*)d_ws;

  // ws layout (header < 1 MB, then h chunk buffer)
  int*    cnt   = (int*)(ws + 0);
  int*    fill  = (int*)(ws + 32);
  int*    pbase = (int*)(ws + 64);
  int*    texp  = (int*)(ws + 128);
  int*    rtok  = (int*)(ws + 1024);
  float*  rwgt  = (float*)(ws + 1024 + (size_t)MAXROWS * 4);
  int2*   toke  = (int2*)(ws + 1024 + (size_t)MAXROWS * 8);
  float2* tokw  = (float2*)(ws + 1024 + (size_t)MAXROWS * 8 + (size_t)T_TOK * 8);
  short*  hbuf  = (short*)(ws + (1 << 20));

  size_t hcap = ws_size > (size_t)(1 << 20) ? ws_size - (1 << 20) : 0;
  int tpc = (int)(hcap / ((size_t)BM * HDIM * 2));   // tiles of h that fit in ws
  if (tpc < 1) return;                               // ws too small to run at all
  if (tpc > MAXTILES) tpc = MAXTILES;

  hipMemsetAsync(d_out, 0, (size_t)T_TOK * DDIM * 4, stream);
  hipMemsetAsync(ws, 0, 128, stream);                        // cnt/fill/pbase
  hipMemsetAsync(rtok, 0xFF, (size_t)MAXROWS * 4, stream);   // rows default -1 (pad)

  k_gate<<<64, 256, 0, stream>>>(x, gw, gb, toke, tokw, cnt);
  k_plan<<<1, 64, 0, stream>>>(cnt, pbase, texp);
  k_scatter<<<T_TOK / 256, 256, 0, stream>>>(toke, tokw, pbase, fill, rtok, rwgt);

  for (int base = 0; base < MAXTILES; base += tpc) {
    int nt = MAXTILES - base;
    if (nt > tpc) nt = tpc;
    k_ffn1<<<dim3(nt, HDIM / 128), 256, 0, stream>>>(x, w1, b1, rtok, texp, base, hbuf);
    k_ffn2<<<dim3(nt, DDIM / 128), 256, 0, stream>>>(hbuf, w2, b2, rtok, rwgt, texp, base, out);
  }
}

// Round 2
// 1181.503 us; speedup vs baseline: 1.0652x; 1.0652x over previous
//
#include <hip/hip_runtime.h>
#include <math.h>

#define T_TOK 8192
#define DDIM  1024
#define HDIM  4096
#define NEXP  8
#define BM    256
#define MAXROWS (T_TOK*2 + NEXP*BM)   /* 18432 */
#define MAXTILES (MAXROWS/BM)         /* 72 */
#define LDA   40                      /* LDS row stride in shorts: 80B = 5*16B -> 2-way max on b128 */

typedef __attribute__((ext_vector_type(8))) short short8;
typedef __attribute__((ext_vector_type(4))) short short4v;
typedef __attribute__((ext_vector_type(4))) float f32x4;

__device__ __forceinline__ short f2bf(float f) {
  unsigned u = __float_as_uint(f);
  u += 0x7fffu + ((u >> 16) & 1u);   // RNE
  return (short)(u >> 16);
}

// ---------------- weight transpose + fp32->bf16: wt[e][c][r] = w[e][r][c] ----------------
__global__ __launch_bounds__(256) void k_tr(const float* __restrict__ w,
                                            short* __restrict__ wt, int R, int C) {
  __shared__ float sl[64][65];
  int e = blockIdx.z;
  const float* W = w + (size_t)e * R * C;
  short* O = wt + (size_t)e * R * C;
  int c0 = blockIdx.x * 64, r0 = blockIdx.y * 64;
  int t = threadIdx.x;
  int lr = t >> 4, lc4 = (t & 15) * 4;
#pragma unroll
  for (int i = 0; i < 4; i++) {
    float4 v = *(const float4*)&W[(size_t)(r0 + lr + i * 16) * C + c0 + lc4];
    sl[lr + i * 16][lc4 + 0] = v.x;
    sl[lr + i * 16][lc4 + 1] = v.y;
    sl[lr + i * 16][lc4 + 2] = v.z;
    sl[lr + i * 16][lc4 + 3] = v.w;
  }
  __syncthreads();
#pragma unroll
  for (int i = 0; i < 4; i++) {
    int oc = lr + i * 16;                 // out row = original col (within tile)
    short4v s;
#pragma unroll
    for (int j = 0; j < 4; j++) s[j] = f2bf(sl[lc4 + j][oc]);
    *(short4v*)&O[(size_t)(c0 + oc) * R + r0 + lc4] = s;
  }
}

// ---------------- gating ----------------
__global__ __launch_bounds__(256) void k_gate(const float* __restrict__ x,
    const float* __restrict__ gw, const float* __restrict__ gb,
    int2* __restrict__ toke, float2* __restrict__ tokw, int* __restrict__ cnt) {
  __shared__ float sg[NEXP * DDIM];           // transposed [e][d], 32 KB
  for (int i = threadIdx.x; i < NEXP * DDIM; i += 256) {
    int e = i >> 10, d = i & (DDIM - 1);
    sg[i] = gw[d * NEXP + e];
  }
  __syncthreads();
  int wave = threadIdx.x >> 6, lane = threadIdx.x & 63;
  int tok0 = blockIdx.x * 32;                 // 32 tokens per block, 256 blocks
  for (int tt = wave; tt < 32; tt += 4) {
    int tok = tok0 + tt;
    float p[NEXP];
#pragma unroll
    for (int e = 0; e < NEXP; e++) p[e] = 0.f;
#pragma unroll
    for (int c = 0; c < 4; c++) {
      int d = c * 256 + lane * 4;
      float4 xv = *(const float4*)&x[(size_t)tok * DDIM + d];
#pragma unroll
      for (int e = 0; e < NEXP; e++) {
        float4 g = *(const float4*)&sg[e * DDIM + d];
        p[e] += xv.x * g.x + xv.y * g.y + xv.z * g.z + xv.w * g.w;
      }
    }
#pragma unroll
    for (int off = 32; off; off >>= 1)
#pragma unroll
      for (int e = 0; e < NEXP; e++) p[e] += __shfl_xor(p[e], off);
    if (lane == 0) {
      float l[NEXP];
#pragma unroll
      for (int e = 0; e < NEXP; e++) l[e] = p[e] + gb[e];
      int i0 = 0;
#pragma unroll
      for (int e = 1; e < NEXP; e++) if (l[e] > l[i0]) i0 = e;   // first-max (jax tie-break)
      int i1 = (i0 == 0) ? 1 : 0;
#pragma unroll
      for (int e = 0; e < NEXP; e++) if (e != i0 && l[e] > l[i1]) i1 = e;
      float ex = expf(l[i1] - l[i0]);
      float w0 = 1.f / (1.f + ex);
      toke[tok] = make_int2(i0, i1);
      tokw[tok] = make_float2(w0, 1.f - w0);
      atomicAdd(&cnt[i0], 1);
      atomicAdd(&cnt[i1], 1);
    }
  }
}

// ---------------- routing plan ----------------
__global__ void k_plan(const int* __restrict__ cnt, int* __restrict__ pbase,
                       int* __restrict__ texp) {
  if (threadIdx.x == 0 && blockIdx.x == 0) {
    int base = 0;
    for (int e = 0; e < NEXP; e++) {
      pbase[e] = base;
      int pc = (cnt[e] + BM - 1) & ~(BM - 1);   // pad each expert to tile multiple
      for (int t = base / BM; t < (base + pc) / BM; ++t) texp[t] = e;
      base += pc;
    }
    for (int t = base / BM; t < MAXTILES; ++t) texp[t] = -1;
  }
}

__global__ __launch_bounds__(256) void k_scatter(const int2* __restrict__ toke,
    const float2* __restrict__ tokw, const int* __restrict__ pbase,
    int* __restrict__ fill, int* __restrict__ rtok, float* __restrict__ rwgt) {
  int tok = blockIdx.x * 256 + threadIdx.x;
  if (tok >= T_TOK) return;
  int2 te = toke[tok];
  float2 tw = tokw[tok];
  int s0 = atomicAdd(&fill[te.x], 1);
  int r0 = pbase[te.x] + s0;
  rtok[r0] = tok; rwgt[r0] = tw.x;
  int s1 = atomicAdd(&fill[te.y], 1);
  int r1 = pbase[te.y] + s1;
  rtok[r1] = tok; rwgt[r1] = tw.y;
}

// ---------------- stage 1: h = gelu(x @ w1[e] + b1[e]) ----------------
// grid (HDIM/128, nt), 512 threads. w1t = [e][n(H)][k(D)] bf16.
__global__ __launch_bounds__(512) void k_ffn1(const float* __restrict__ x,
    const short* __restrict__ w1t, const float* __restrict__ b1,
    const int* __restrict__ rtok, const int* __restrict__ texp,
    int tile_base, short* __restrict__ hbuf) {
  int tl = blockIdx.y;
  int tm = tile_base + tl;
  int e = texp[tm];
  if (e < 0) return;
  int n0 = blockIdx.x * 128;
  const short* W = w1t + (size_t)e * HDIM * DDIM;
  __shared__ short Al[BM * LDA];
  __shared__ short Bl[128 * LDA];
  int t = threadIdx.x;
  int ar  = t >> 1;          // A row 0..255
  int ah  = t & 1;           // k half (16 shorts)
  int br  = t >> 2;          // B row 0..127
  int bs  = t & 3;           // k seg (8 shorts)
  int atok = rtok[tm * BM + ar];

  f32x4 acc[4][4];
#pragma unroll
  for (int i = 0; i < 4; i++)
#pragma unroll
    for (int j = 0; j < 4; j++) acc[i][j] = (f32x4){0.f, 0.f, 0.f, 0.f};

  int wid = t >> 6, lane = t & 63;
  int wm = (wid >> 1) * 64, wn = (wid & 1) * 64;
  int lr = lane & 15, kg = lane >> 4;

  for (int kt = 0; kt < DDIM / 32; ++kt) {
    int k0 = kt * 32;
    __syncthreads();
    {
      short8 s0 = {0,0,0,0,0,0,0,0}, s1 = {0,0,0,0,0,0,0,0};
      if (atok >= 0) {
        const float* xp = &x[(size_t)atok * DDIM + k0 + ah * 16];
        float4 f0 = *(const float4*)&xp[0],  f1 = *(const float4*)&xp[4];
        float4 f2 = *(const float4*)&xp[8],  f3 = *(const float4*)&xp[12];
        s0[0]=f2bf(f0.x); s0[1]=f2bf(f0.y); s0[2]=f2bf(f0.z); s0[3]=f2bf(f0.w);
        s0[4]=f2bf(f1.x); s0[5]=f2bf(f1.y); s0[6]=f2bf(f1.z); s0[7]=f2bf(f1.w);
        s1[0]=f2bf(f2.x); s1[1]=f2bf(f2.y); s1[2]=f2bf(f2.z); s1[3]=f2bf(f2.w);
        s1[4]=f2bf(f3.x); s1[5]=f2bf(f3.y); s1[6]=f2bf(f3.z); s1[7]=f2bf(f3.w);
      }
      *(short8*)&Al[ar * LDA + ah * 16 + 0] = s0;
      *(short8*)&Al[ar * LDA + ah * 16 + 8] = s1;
    }
    *(short8*)&Bl[br * LDA + bs * 8] =
        *(const short8*)&W[(size_t)(n0 + br) * DDIM + k0 + bs * 8];
    __syncthreads();
    short8 af[4], bg[4];
#pragma unroll
    for (int i = 0; i < 4; i++) af[i] = *(short8*)&Al[(wm + i * 16 + lr) * LDA + kg * 8];
#pragma unroll
    for (int j = 0; j < 4; j++) bg[j] = *(short8*)&Bl[(wn + j * 16 + lr) * LDA + kg * 8];
#pragma unroll
    for (int i = 0; i < 4; i++)
#pragma unroll
      for (int j = 0; j < 4; j++)
        acc[i][j] = __builtin_amdgcn_mfma_f32_16x16x32_bf16(af[i], bg[j], acc[i][j], 0, 0, 0);
  }

#pragma unroll
  for (int j = 0; j < 4; j++) {
    int gcol = n0 + wn + j * 16 + lr;
    float bias = b1[e * HDIM + gcol];
#pragma unroll
    for (int i = 0; i < 4; i++) {
      int rl = wm + i * 16 + kg * 4;
#pragma unroll
      for (int r = 0; r < 4; r++) {
        float v = acc[i][j][r] + bias;
        v = 0.5f * v * (1.f + erff(v * 0.70710678118f));   // exact gelu
        hbuf[(size_t)(tl * BM + rl + r) * HDIM + gcol] = f2bf(v);
      }
    }
  }
}

// ---------------- stage 2: out[tok] += wgt * (h @ w2[e] + b2[e]) ----------------
// grid (DDIM/128, nt), 512 threads. w2t = [e][n(D)][k(H)] bf16.
__global__ __launch_bounds__(512) void k_ffn2(const short* __restrict__ hbuf,
    const short* __restrict__ w2t, const float* __restrict__ b2,
    const int* __restrict__ rtok, const float* __restrict__ rwgt,
    const int* __restrict__ texp, int tile_base, float* __restrict__ out) {
  int tl = blockIdx.y;
  int tm = tile_base + tl;
  int e = texp[tm];
  if (e < 0) return;
  int n0 = blockIdx.x * 128;
  const short* W = w2t + (size_t)e * DDIM * HDIM;
  __shared__ short Al[BM * LDA];
  __shared__ short Bl[128 * LDA];
  int t = threadIdx.x;
  int ar  = t >> 1;
  int ah  = t & 1;
  int br  = t >> 2;
  int bs  = t & 3;

  f32x4 acc[4][4];
#pragma unroll
  for (int i = 0; i < 4; i++)
#pragma unroll
    for (int j = 0; j < 4; j++) acc[i][j] = (f32x4){0.f, 0.f, 0.f, 0.f};

  int wid = t >> 6, lane = t & 63;
  int wm = (wid >> 1) * 64, wn = (wid & 1) * 64;
  int lr = lane & 15, kg = lane >> 4;

  for (int kt = 0; kt < HDIM / 32; ++kt) {
    int k0 = kt * 32;
    __syncthreads();
    {
      const short* hp = &hbuf[(size_t)(tl * BM + ar) * HDIM + k0 + ah * 16];
      *(short8*)&Al[ar * LDA + ah * 16 + 0] = *(const short8*)&hp[0];
      *(short8*)&Al[ar * LDA + ah * 16 + 8] = *(const short8*)&hp[8];
    }
    *(short8*)&Bl[br * LDA + bs * 8] =
        *(const short8*)&W[(size_t)(n0 + br) * HDIM + k0 + bs * 8];
    __syncthreads();
    short8 af[4], bg[4];
#pragma unroll
    for (int i = 0; i < 4; i++) af[i] = *(short8*)&Al[(wm + i * 16 + lr) * LDA + kg * 8];
#pragma unroll
    for (int j = 0; j < 4; j++) bg[j] = *(short8*)&Bl[(wn + j * 16 + lr) * LDA + kg * 8];
#pragma unroll
    for (int i = 0; i < 4; i++)
#pragma unroll
      for (int j = 0; j < 4; j++)
        acc[i][j] = __builtin_amdgcn_mfma_f32_16x16x32_bf16(af[i], bg[j], acc[i][j], 0, 0, 0);
  }

#pragma unroll
  for (int j = 0; j < 4; j++) {
    int gcol = n0 + wn + j * 16 + lr;
    float bias = b2[e * DDIM + gcol];
#pragma unroll
    for (int i = 0; i < 4; i++) {
      int rl = wm + i * 16 + kg * 4;
#pragma unroll
      for (int r = 0; r < 4; r++) {
        int grow = tm * BM + rl + r;
        int tok = rtok[grow];
        if (tok >= 0) {
          float v = (acc[i][j][r] + bias) * rwgt[grow];
          atomicAdd(&out[(size_t)tok * DDIM + gcol], v);
        }
      }
    }
  }
}

extern "C" void kernel_launch(void* const* d_in, const int* in_sizes, int n_in,
                              void* d_out, int out_size, void* d_ws, size_t ws_size,
                              hipStream_t stream) {
  const float* x  = (const float*)d_in[0];
  const float* gw = (const float*)d_in[1];
  const float* gb = (const float*)d_in[2];
  const float* w1 = (const float*)d_in[3];
  const float* b1 = (const float*)d_in[4];
  const float* w2 = (const float*)d_in[5];
  const float* b2 = (const float*)d_in[6];
  float* out = (float*)d_out;
  char* ws = (char*)d_ws;

  // ws layout: 1MB header | w1t 67.1MB | w2t 67.1MB | hbuf (chunked)
  int*    cnt   = (int*)(ws + 0);
  int*    fill  = (int*)(ws + 32);
  int*    pbase = (int*)(ws + 64);
  int*    texp  = (int*)(ws + 128);
  int*    rtok  = (int*)(ws + 1024);
  float*  rwgt  = (float*)(ws + 1024 + (size_t)MAXROWS * 4);
  int2*   toke  = (int2*)(ws + 1024 + (size_t)MAXROWS * 8);
  float2* tokw  = (float2*)(ws + 1024 + (size_t)MAXROWS * 8 + (size_t)T_TOK * 8);
  size_t wbytes = (size_t)NEXP * DDIM * HDIM * 2;   // 67.1 MB each
  short*  w1t   = (short*)(ws + (1 << 20));
  short*  w2t   = (short*)(ws + (1 << 20) + wbytes);
  size_t hoff   = (1 << 20) + 2 * wbytes;
  short*  hbuf  = (short*)(ws + hoff);

  size_t hcap = ws_size > hoff ? ws_size - hoff : 0;
  int tpc = (int)(hcap / ((size_t)BM * HDIM * 2));   // 2MB per tile of h
  if (tpc < 1) return;                               // ws too small
  if (tpc > MAXTILES) tpc = MAXTILES;

  hipMemsetAsync(d_out, 0, (size_t)T_TOK * DDIM * 4, stream);
  hipMemsetAsync(ws, 0, 128, stream);                        // cnt/fill/pbase
  hipMemsetAsync(rtok, 0xFF, (size_t)MAXROWS * 4, stream);   // rows default -1 (pad)

  // weight transpose/downconvert: w1 [e][D][H] -> w1t [e][H][D]; w2 [e][H][D] -> w2t [e][D][H]
  k_tr<<<dim3(HDIM / 64, DDIM / 64, NEXP), 256, 0, stream>>>(w1, w1t, DDIM, HDIM);
  k_tr<<<dim3(DDIM / 64, HDIM / 64, NEXP), 256, 0, stream>>>(w2, w2t, HDIM, DDIM);

  k_gate<<<256, 256, 0, stream>>>(x, gw, gb, toke, tokw, cnt);
  k_plan<<<1, 64, 0, stream>>>(cnt, pbase, texp);
  k_scatter<<<T_TOK / 256, 256, 0, stream>>>(toke, tokw, pbase, fill, rtok, rwgt);

  for (int base = 0; base < MAXTILES; base += tpc) {
    int nt = MAXTILES - base;
    if (nt > tpc) nt = tpc;
    k_ffn1<<<dim3(HDIM / 128, nt), 512, 0, stream>>>(x, w1t, b1, rtok, texp, base, hbuf);
    k_ffn2<<<dim3(DDIM / 128, nt), 512, 0, stream>>>(hbuf, w2t, b2, rtok, rwgt, texp, base, out);
  }
}